// Round 1
// 1219.981 us; speedup vs baseline: 1.9674x; 1.9674x over previous
//
#include <hip/hip_runtime.h>
#include <cstdint>

// Problem constants (fixed by reference: B=16, L=1024, EMBED=1024, 8 heads x 128)
#define EMBED 1024
#define NHEAD 8
#define HID   128
#define MB    16
#define LEN   1024
#define MROWS (MB*LEN)   // 16384 rows for the (b,l)-flattened GEMMs
#define BHT   (NHEAD*MB) // 128 batched heads, bh = h*16 + b

// bf16 fragment types for mfma_f32_16x16x32_bf16 (guide-verified on gfx950)
typedef short bf16x8  __attribute__((ext_vector_type(8)));
typedef short short4v __attribute__((ext_vector_type(4)));
typedef float f32x4   __attribute__((ext_vector_type(4)));

static __device__ __forceinline__ short f2bf(float f) {
    // round-to-nearest-even fp32 -> bf16 (finite inputs only)
    unsigned int x = __builtin_bit_cast(unsigned int, f);
    x += 0x7fffu + ((x >> 16) & 1u);
    return (short)(x >> 16);
}
static __device__ __forceinline__ float bf2f(short u) {
    return __builtin_bit_cast(float, (unsigned int)((unsigned short)u) << 16);
}

// ---------------------------------------------------------------------------
// Unified bf16-MFMA GEMM, 128x128 tile, BK=32, 256 threads (4 waves, 2x2),
// each wave 64x64 = 4x4 fragments of 16x16x32. Reg-staged LDS with padded
// stride 40 (80 B) so frag ds_read_b128 avoids the 8-way linear conflict.
// C[m,n] = sum_k A[m,k]*B[n,k]  (B given N-major, k-contiguous = B^T GEMM).
//
// MODE 0 (linear): A = X fp32 (MROWS x 1024), B = W fp32 (1024 x 1024),
//                  C -> kxT bf16 [bh][hh][l] (+bias), grid (N/128, M/128)
// MODE 1 (attn):   A = score fp32 (per-bh 1024x1024), B = kxT[bh] bf16 (128x1024),
//                  C -> attnb bf16 [bh][q][hh], grid (M/128, BHT)
// MODE 2 (proj):   A = attnb bf16 head-scattered (MROWS x 1024), B = Wp fp32,
//                  C -> out fp32 (+bias), grid (N/128, M/128)
// ---------------------------------------------------------------------------
template<int MODE>
__global__ __launch_bounds__(256)
void k_gemm(const float* __restrict__ Af, const short* __restrict__ Ab,
            const float* __restrict__ Bf, const short* __restrict__ Bb,
            const float* __restrict__ bias,
            float* __restrict__ Cf, short* __restrict__ Cb)
{
    __shared__ short As[128*40];
    __shared__ short Bs[128*40];
    const int tid  = threadIdx.x;
    const int lane = tid & 63, wv = tid >> 6, wr = wv >> 1, wc = wv & 1;
    const int lr   = lane & 15, kg = lane >> 4;
    const int sr   = tid >> 1, sh = tid & 1;   // staging: row, which 16-elem half

    int M0, N0, bh = 0;
    if constexpr (MODE == 1) { M0 = blockIdx.x * 128; N0 = 0; bh = blockIdx.y; }
    else                     { M0 = blockIdx.y * 128; N0 = blockIdx.x * 128; }

    f32x4 acc[4][4] = {};

    for (int k0 = 0; k0 < 1024; k0 += 32) {
        // ---- stage A tile (128 rows x 32 k) into padded LDS ----
        if constexpr (MODE == 2) {
            // attnb bf16, logical A[m][k]: m=b*1024+l, k=h*128+hh,
            // stored at [((h*16+b)*1024+l)*128 + hh]
            const short* ap = Ab
                + ((size_t)((k0 >> 7)*MB + (M0 >> 10)) * LEN + (M0 & 1023) + sr) * HID
                + (k0 & 127) + sh*16;
            bf16x8 v0 = *(const bf16x8*)(ap);
            bf16x8 v1 = *(const bf16x8*)(ap + 8);
            *(bf16x8*)&As[sr*40 + sh*16]     = v0;
            *(bf16x8*)&As[sr*40 + sh*16 + 8] = v1;
        } else {
            const float* ap = (MODE == 0)
                ? (Af + (size_t)(M0 + sr) * 1024 + k0 + sh*16)
                : (Af + ((size_t)bh * LEN + M0 + sr) * 1024 + k0 + sh*16);
            #pragma unroll
            for (int c = 0; c < 4; ++c) {
                float4 v = *(const float4*)(ap + c*4);
                short4v u;
                u[0] = f2bf(v.x); u[1] = f2bf(v.y); u[2] = f2bf(v.z); u[3] = f2bf(v.w);
                *(short4v*)&As[sr*40 + sh*16 + c*4] = u;
            }
        }
        // ---- stage B tile (128 rows x 32 k) ----
        if constexpr (MODE == 1) {
            const short* bp = Bb + (size_t)bh*HID*LEN + (size_t)sr*LEN + k0 + sh*16;
            bf16x8 v0 = *(const bf16x8*)(bp);
            bf16x8 v1 = *(const bf16x8*)(bp + 8);
            *(bf16x8*)&Bs[sr*40 + sh*16]     = v0;
            *(bf16x8*)&Bs[sr*40 + sh*16 + 8] = v1;
        } else {
            const float* bp = Bf + (size_t)(N0 + sr) * 1024 + k0 + sh*16;
            #pragma unroll
            for (int c = 0; c < 4; ++c) {
                float4 v = *(const float4*)(bp + c*4);
                short4v u;
                u[0] = f2bf(v.x); u[1] = f2bf(v.y); u[2] = f2bf(v.z); u[3] = f2bf(v.w);
                *(short4v*)&Bs[sr*40 + sh*16 + c*4] = u;
            }
        }
        __syncthreads();
        bf16x8 a[4], b[4];
        #pragma unroll
        for (int i = 0; i < 4; ++i)
            a[i] = *(const bf16x8*)&As[(wr*64 + i*16 + lr)*40 + kg*8];
        #pragma unroll
        for (int j = 0; j < 4; ++j)
            b[j] = *(const bf16x8*)&Bs[(wc*64 + j*16 + lr)*40 + kg*8];
        #pragma unroll
        for (int i = 0; i < 4; ++i)
            #pragma unroll
            for (int j = 0; j < 4; ++j)
                acc[i][j] = __builtin_amdgcn_mfma_f32_16x16x32_bf16(a[i], b[j], acc[i][j], 0, 0, 0);
        __syncthreads();
    }

    // ---- epilogue. C/D layout: col = lane&15, row = (lane>>4)*4 + reg ----
    if constexpr (MODE == 0) {
        const int bv = M0 >> 10;
        const int l0base = (M0 & 1023) + wr*64 + kg*4;
        #pragma unroll
        for (int j = 0; j < 4; ++j) {
            const int hh = wc*64 + j*16 + lr;
            const float bval = bias[N0 + hh];
            const size_t rowbase = ((size_t)((N0 >> 7)*MB + bv) * HID + hh) * LEN;
            #pragma unroll
            for (int i = 0; i < 4; ++i) {
                short4v u;
                #pragma unroll
                for (int r = 0; r < 4; ++r) u[r] = f2bf(acc[i][j][r] + bval);
                *(short4v*)&Cb[rowbase + l0base + i*16] = u;
            }
        }
    } else if constexpr (MODE == 1) {
        #pragma unroll
        for (int i = 0; i < 4; ++i) {
            const int mq = M0 + wr*64 + i*16 + kg*4;
            #pragma unroll
            for (int r = 0; r < 4; ++r) {
                short* orow = Cb + ((size_t)bh*LEN + mq + r)*HID + wc*64 + lr;
                #pragma unroll
                for (int j = 0; j < 4; ++j) orow[j*16] = f2bf(acc[i][j][r]);
            }
        }
    } else {
        #pragma unroll
        for (int i = 0; i < 4; ++i) {
            const int m = M0 + wr*64 + i*16 + kg*4;
            #pragma unroll
            for (int r = 0; r < 4; ++r) {
                float* orow = Cf + (size_t)(m + r)*EMBED + N0 + wc*64 + lr;
                #pragma unroll
                for (int j = 0; j < 4; ++j)
                    orow[j*16] = acc[i][j][r] + bias[N0 + wc*64 + j*16 + lr];
            }
        }
    }
}

// ---------------------------------------------------------------------------
// sk[bh,l] = sum_hh kxT[bh,hh,l]*w[hh] ; sq likewise with w[128:].
// kxT is bf16 [bh][hh][l]: consecutive threads read consecutive l -> coalesced.
// ---------------------------------------------------------------------------
__global__ __launch_bounds__(256)
void k_rowdot2(const short* __restrict__ kxT, const short* __restrict__ qxT,
               const float* __restrict__ w, float* __restrict__ sk,
               float* __restrict__ sq)
{
    const int gid = blockIdx.x * 256 + threadIdx.x;   // 0 .. 2*BHT*LEN-1
    const short* src; const float* wp; float* dst; int rid;
    if (gid < BHT*LEN) { src = kxT; wp = w;       dst = sk; rid = gid; }
    else               { src = qxT; wp = w + HID; dst = sq; rid = gid - BHT*LEN; }
    const int bh = rid >> 10, l = rid & 1023;
    const short* base = src + (size_t)bh * HID * LEN + l;
    float acc = 0.f;
    #pragma unroll 8
    for (int hh = 0; hh < HID; ++hh)
        acc += bf2f(base[(size_t)hh * LEN]) * wp[hh];
    dst[rid] = acc;
}

// ---------------------------------------------------------------------------
// score[bh,q,k] = softmax_k( tanh(sq[bh,q] + sk[bh,k]) )  (unchanged, fp32)
// ---------------------------------------------------------------------------
__global__ __launch_bounds__(256)
void k_softmax(const float* __restrict__ sk, const float* __restrict__ sq,
               float* __restrict__ score)
{
    const int bh = blockIdx.y;
    const int qr = blockIdx.x;
    const float sqv = sq[bh*LEN + qr];
    const float* skr = sk + (size_t)bh*LEN;
    const int t = threadIdx.x;
    float e[4];
    float sum = 0.f;
    #pragma unroll
    for (int i = 0; i < 4; ++i) {
        const float x  = sqv + skr[t + 256*i];
        const float t2 = __expf(2.f * x);                            // e^{2x}
        const float th = 1.f - 2.f * __builtin_amdgcn_rcpf(t2 + 1.f); // tanh(x)
        e[i] = __expf(th);
        sum += e[i];
    }
    __shared__ float red[4];
    #pragma unroll
    for (int off = 32; off; off >>= 1) sum += __shfl_down(sum, off);
    if ((t & 63) == 0) red[t >> 6] = sum;
    __syncthreads();
    const float inv = __builtin_amdgcn_rcpf(red[0] + red[1] + red[2] + red[3]);
    float* out = score + ((size_t)bh*LEN + qr)*LEN;
    #pragma unroll
    for (int i = 0; i < 4; ++i) out[t + 256*i] = e[i] * inv;
}

extern "C" void kernel_launch(void* const* d_in, const int* in_sizes, int n_in,
                              void* d_out, int out_size, void* d_ws, size_t ws_size,
                              hipStream_t stream)
{
    const float* k  = (const float*)d_in[0];
    const float* q  = (const float*)d_in[1];
    const float* Wk = (const float*)d_in[2];
    const float* bk = (const float*)d_in[3];
    const float* Wq = (const float*)d_in[4];
    const float* bq = (const float*)d_in[5];
    const float* w  = (const float*)d_in[6];
    const float* Wp = (const float*)d_in[7];
    const float* bp = (const float*)d_in[8];

    float* out   = (float*)d_out;                    // (16,1024,1024)
    float* score = out + (size_t)MROWS*EMBED;        // (128,1024,1024)

    // Workspace: kxT | qxT | sk | sq   (bf16 kxT/qxT = 32 MB each; total 68 MB)
    // attnb (bf16, 32 MB) aliases qxT: qxT is dead after k_rowdot2.
    short* kxT = (short*)d_ws;
    short* qxT = kxT + (size_t)BHT*HID*LEN;
    float* sk  = (float*)(qxT + (size_t)BHT*HID*LEN);
    float* sq  = sk + (size_t)BHT*LEN;
    short* attnb = qxT;

    const dim3 gMN(EMBED/128, MROWS/128);   // (8,128)
    const dim3 gAT(LEN/128, BHT);           // (8,128)

    k_gemm<0><<<gMN, 256, 0, stream>>>(k, nullptr, Wk, nullptr, bk, nullptr, kxT);
    k_gemm<0><<<gMN, 256, 0, stream>>>(q, nullptr, Wq, nullptr, bq, nullptr, qxT);
    k_rowdot2<<<(2*BHT*LEN)/256, 256, 0, stream>>>(kxT, qxT, w, sk, sq);
    k_softmax<<<dim3(LEN, BHT), 256, 0, stream>>>(sk, sq, score);
    k_gemm<1><<<gAT, 256, 0, stream>>>(score, nullptr, nullptr, kxT, nullptr, nullptr, attnb);
    k_gemm<2><<<gMN, 256, 0, stream>>>(nullptr, attnb, Wp, nullptr, bp, out, nullptr);
}